// Round 16
// baseline (31.704 us; speedup 1.0000x reference)
//
#include <hip/hip_runtime.h>

// RoiAlign: fm (4,256,50,50) f32, boxes (512,4), box_idx (512) -> out (512,256,14,14) f32
//
// R16: shrink the additive read/compute budget (R12: full 30.0 = stores 17.1
// + read/compute 12.5, perfectly additive; stagger R14b null).
//  1) No divide chains: /13.0f -> hoisted (v2-v1)*(1/13) + fma per coord
//     (v_div_* ~9 instr x8/lane removed). Bilinear is continuous in coords ->
//     1-ulp shift harmless except measure-zero validity-boundary flips.
//  2) Block = one box x 32 channels (two 16-ch items, two 16KB LDS buffers):
//     weight setup + box loads ONCE per 32 ch (was per 16).
//  3) DMA(A)+DMA(B) issued up front; vmcnt(4) -> comp(A); vmcnt(4) (retires
//     DMA(B), stores(A) stay in flight under comp(B)) -> comp(B). Halves
//     end-of-wave store drains; box loads precede all stores (no compiler
//     vmcnt(0) mid-stream -- R13's hidden bug).
// Keeps: R9 channel-slab XCD tiling (XCD k owns ch [32k,32k+32) for all
// boxes, 1.28MB L2-resident); wave-autonomous DMA staging (global_load_lds
// 16B, one instr per plane window); taps at w00+{0,1,16,17}; validity folded
// into x-weights; quad dwordx4 NT stores.

typedef float f32x4 __attribute__((ext_vector_type(4)));

constexpr int C_DIM = 256;
constexpr int H_DIM = 50;
constexpr int W_DIM = 50;
constexpr int M_BOX = 512;
constexpr int CW    = 14;
constexpr int NPOS  = 196;            // 14*14 output positions
constexpr int CCH   = 16;             // channels per item (4 waves x 4)
constexpr int PLANE  = H_DIM * W_DIM; // 2500
constexpr int WC  = 16;               // window cols
constexpr int WSZ = 256;              // 16x16 window floats per plane
constexpr float INV_STRIDE = 1.0f / 16.0f;
constexpr float INV13 = 1.0f / 13.0f;

__global__ __launch_bounds__(256) void roi_align_v16(
    const float* __restrict__ fm,
    const float* __restrict__ boxes,
    const int*   __restrict__ box_idx,
    float*       __restrict__ out)
{
    __shared__ float WA[CCH * WSZ];   // 16 KB (item A)
    __shared__ float WB[CCH * WSZ];   // 16 KB (item B) -> 32 KB, 5 blocks/CU

    // XCD k = bid&7 owns channels [32k, 32k+32); block = (xcd, box).
    int bid = blockIdx.x;
    int xcd = bid & 7;
    int m   = bid >> 3;               // box 0..511
    int cb0 = xcd * 32;               // item A channels
    int cb1 = cb0 + CCH;              // item B channels

    int t  = threadIdx.x;
    int wv = t >> 6;                  // wave 0..3 -> 4 planes per item
    int l  = t & 63;

    float4 bx = reinterpret_cast<const float4*>(boxes)[m];
    int bi = box_idx[m];
    float x1 = bx.x * INV_STRIDE;
    float y1 = bx.y * INV_STRIDE;
    float x2 = bx.z * INV_STRIDE;
    float y2 = bx.w * INV_STRIDE;

    int xLo = min(max((int)floorf(x1), 0), W_DIM - 1);
    int yLo = min(max((int)floorf(y1), 0), H_DIM - 1);
    int xW  = min(xLo, W_DIM - WC);   // window cols xW..xW+15 always in-bounds

    // ---- DMA both items up front (wave-autonomous; 8 instrs/wave) ----
    {
        int row  = l >> 2;            // 0..15
        int quad = l & 3;             // cols 4quad..4quad+3
        int gy   = min(yLo + row, H_DIM - 1);   // row clamp-duplicate
        const float* gA = fm + ((size_t)(bi * C_DIM + cb0 + wv * 4)) * PLANE
                             + gy * W_DIM + xW + quad * 4;
        const float* gB = fm + ((size_t)(bi * C_DIM + cb1 + wv * 4)) * PLANE
                             + gy * W_DIM + xW + quad * 4;
        #pragma unroll
        for (int k = 0; k < 4; ++k) {
            __builtin_amdgcn_global_load_lds(
                (const __attribute__((address_space(1))) unsigned int*)(gA + (size_t)k * PLANE),
                (__attribute__((address_space(3))) unsigned int*)&WA[(wv * 4 + k) * WSZ],
                16, 0, 0);
        }
        #pragma unroll
        for (int k = 0; k < 4; ++k) {
            __builtin_amdgcn_global_load_lds(
                (const __attribute__((address_space(1))) unsigned int*)(gB + (size_t)k * PLANE),
                (__attribute__((address_space(3))) unsigned int*)&WB[(wv * 4 + k) * WSZ],
                16, 0, 0);
        }
    }

    // ---- weight setup ONCE (no divides; overlaps DMA flight) ----
    int   w00[4];
    float wxv[4], owx[4], wyv[4], owy[4];
    float* opA;
    if (l < 49) {
        int q = l;
        float sy = (y2 - y1) * INV13;
        float sx = (x2 - x1) * INV13;
        #pragma unroll
        for (int e = 0; e < 4; ++e) {
            int p  = 4 * q + e;
            int iy = p / CW;
            int ix = p - iy * CW;
            float ys = y1 + (float)iy * sy;
            float xs = x1 + (float)ix * sx;
            float y0f = floorf(ys);
            float x0f = floorf(xs);
            float wy = ys - y0f;
            float wx = xs - x0f;
            int y0i = min(max((int)y0f, 0), H_DIM - 1);
            int x0i = min(max((int)x0f, 0), W_DIM - 1);
            bool vld = (ys >= 0.0f) && (ys <= (float)(H_DIM - 1)) &&
                       (xs >= 0.0f) && (xs <= (float)(W_DIM - 1));
            w00[e] = (y0i - yLo) * WC + (x0i - xW);
            wxv[e] = vld ? wx : 0.0f;   // invalid -> both x-weights 0 -> exact 0
            owx[e] = vld ? (1.0f - wx) : 0.0f;
            wyv[e] = wy; owy[e] = 1.0f - wy;
        }
        opA = out + ((size_t)m * C_DIM + cb0 + wv * 4) * NPOS + 4 * q;
    }

    // ---- item A: wait own 4 DMAs (vmcnt 8 -> 4 retires DMA(A)) ----
    asm volatile("s_waitcnt vmcnt(4)" ::: "memory");
    if (l < 49) {
        const float* wp = &WA[(size_t)(wv * 4) * WSZ];
        float* op = opA;
        #pragma unroll
        for (int k = 0; k < 4; ++k) {
            float rv[4];
            #pragma unroll
            for (int e = 0; e < 4; ++e) {
                float f00 = wp[w00[e]];
                float f01 = wp[w00[e] + 1];
                float f10 = wp[w00[e] + WC];
                float f11 = wp[w00[e] + WC + 1];
                float top = f00 * owx[e] + f01 * wxv[e];
                float bot = f10 * owx[e] + f11 * wxv[e];
                rv[e] = top * owy[e] + bot * wyv[e];
            }
            f32x4 r;
            r.x = rv[0]; r.y = rv[1]; r.z = rv[2]; r.w = rv[3];
            __builtin_nontemporal_store(r, reinterpret_cast<f32x4*>(op));
            wp += WSZ;
            op += NPOS;
        }
    }

    // ---- item B: vmcnt(4) retires DMA(B); stores(A) (<=4) stay in flight ----
    asm volatile("s_waitcnt vmcnt(4)" ::: "memory");
    if (l < 49) {
        const float* wp = &WB[(size_t)(wv * 4) * WSZ];
        float* op = opA + (size_t)CCH * NPOS;   // same box, +16 channels
        #pragma unroll
        for (int k = 0; k < 4; ++k) {
            float rv[4];
            #pragma unroll
            for (int e = 0; e < 4; ++e) {
                float f00 = wp[w00[e]];
                float f01 = wp[w00[e] + 1];
                float f10 = wp[w00[e] + WC];
                float f11 = wp[w00[e] + WC + 1];
                float top = f00 * owx[e] + f01 * wxv[e];
                float bot = f10 * owx[e] + f11 * wxv[e];
                rv[e] = top * owy[e] + bot * wyv[e];
            }
            f32x4 r;
            r.x = rv[0]; r.y = rv[1]; r.z = rv[2]; r.w = rv[3];
            __builtin_nontemporal_store(r, reinterpret_cast<f32x4*>(op));
            wp += WSZ;
            op += NPOS;
        }
    }
}

extern "C" void kernel_launch(void* const* d_in, const int* in_sizes, int n_in,
                              void* d_out, int out_size, void* d_ws, size_t ws_size,
                              hipStream_t stream) {
    const float* fm      = (const float*)d_in[0];
    const float* boxes   = (const float*)d_in[1];
    const int*   box_idx = (const int*)d_in[2];
    float* out = (float*)d_out;

    dim3 block(256);
    dim3 grid(M_BOX * 8);   // 4096 blocks: (xcd, box)
    hipLaunchKernelGGL(roi_align_v16, grid, block, 0, stream,
                       fm, boxes, box_idx, out);
}

// Round 17
// 29.859 us; speedup vs baseline: 1.0618x; 1.0618x over previous
//
#include <hip/hip_runtime.h>

// RoiAlign: fm (4,256,50,50) f32, boxes (512,4), box_idx (512) -> out (512,256,14,14) f32
//
// R17: deep per-wave pipeline (R13 fixed). 8 items/block (2 boxes x 4
// sub-slabs of 8 ch), double-buffered wave-private LDS, prefetch distance 1
// realized as: wait D(j) -> comp(buffer j) -> restage item j+2 into the same
// buffer (safe: comp's ds_reads retire before the restage issues in-wave).
// All global scalar loads hoisted (asm keep-alives); steady vmcnt(4); plain
// stores (L2-ack acceptance; L2 = elasticity buffer). R9 channel-slab XCD
// tiling kept. No divides.

typedef float f32x4 __attribute__((ext_vector_type(4)));

constexpr int C_DIM = 256;
constexpr int H_DIM = 50;
constexpr int W_DIM = 50;
constexpr int CW    = 14;
constexpr int NPOS  = 196;
constexpr int PLANE = H_DIM * W_DIM;
constexpr int WC    = 16;
constexpr int WSZ   = 256;
constexpr int ITEM_CH = 8;
constexpr float INV_STRIDE = 1.0f / 16.0f;
constexpr float INV13 = 1.0f / 13.0f;

struct SC { int bi, yLo, xW; float x1, y1, sx, sy; };
struct WT { int w00[4]; float wx[4], ox[4], wy[4], oy[4]; };

__device__ __forceinline__ SC mk_sc(const float* boxes, const int* bidx, int m) {
    float4 bx = reinterpret_cast<const float4*>(boxes)[m];
    SC s;
    s.bi = bidx[m];
    s.x1 = bx.x * INV_STRIDE;
    s.y1 = bx.y * INV_STRIDE;
    s.sx = (bx.z * INV_STRIDE - s.x1) * INV13;
    s.sy = (bx.w * INV_STRIDE - s.y1) * INV13;
    int xLo = min(max((int)floorf(s.x1), 0), W_DIM - 1);
    s.yLo = min(max((int)floorf(s.y1), 0), H_DIM - 1);
    s.xW  = min(xLo, W_DIM - WC);
    return s;
}

__device__ __forceinline__ void mk_wt(const SC& s, int q, WT& W) {
    #pragma unroll
    for (int e = 0; e < 4; ++e) {
        int p  = 4 * q + e;
        int iy = p / CW;
        int ix = p - iy * CW;
        float ys = s.y1 + (float)iy * s.sy;
        float xs = s.x1 + (float)ix * s.sx;
        float y0f = floorf(ys);
        float x0f = floorf(xs);
        float wy = ys - y0f;
        float wx = xs - x0f;
        int y0i = min(max((int)y0f, 0), H_DIM - 1);
        int x0i = min(max((int)x0f, 0), W_DIM - 1);
        bool v = (ys >= 0.0f) && (ys <= (float)(H_DIM - 1)) &&
                 (xs >= 0.0f) && (xs <= (float)(W_DIM - 1));
        W.w00[e] = (y0i - s.yLo) * WC + (x0i - s.xW);
        W.wx[e] = v ? wx : 0.0f;
        W.ox[e] = v ? (1.0f - wx) : 0.0f;
        W.wy[e] = wy; W.oy[e] = 1.0f - wy;
    }
}

__device__ __forceinline__ void stage(const float* fm, const SC& s, int cb,
                                      int wv, int l, float* buf) {
    int row  = l >> 2;
    int quad = l & 3;
    int gy   = min(s.yLo + row, H_DIM - 1);
    const float* g0 = fm + ((size_t)(s.bi * C_DIM + cb + wv * 2)) * PLANE
                         + gy * W_DIM + s.xW + quad * 4;
    float* l0 = &buf[(wv * 2) * WSZ];
    __builtin_amdgcn_global_load_lds(
        (const __attribute__((address_space(1))) unsigned int*)g0,
        (__attribute__((address_space(3))) unsigned int*)l0, 16, 0, 0);
    __builtin_amdgcn_global_load_lds(
        (const __attribute__((address_space(1))) unsigned int*)(g0 + PLANE),
        (__attribute__((address_space(3))) unsigned int*)(l0 + WSZ), 16, 0, 0);
}

__device__ __forceinline__ void comp(const float* buf, const WT& W, float* out,
                                     int m, int cb, int wv, int q) {
    const float* wp = &buf[(wv * 2) * WSZ];
    float* op = out + ((size_t)m * C_DIM + cb + wv * 2) * NPOS + 4 * q;
    #pragma unroll
    for (int k = 0; k < 2; ++k) {
        float rv[4];
        #pragma unroll
        for (int e = 0; e < 4; ++e) {
            float f00 = wp[W.w00[e]];
            float f01 = wp[W.w00[e] + 1];
            float f10 = wp[W.w00[e] + WC];
            float f11 = wp[W.w00[e] + WC + 1];
            float top = f00 * W.ox[e] + f01 * W.wx[e];
            float bot = f10 * W.ox[e] + f11 * W.wx[e];
            rv[e] = top * W.oy[e] + bot * W.wy[e];
        }
        f32x4 r;
        r.x = rv[0]; r.y = rv[1]; r.z = rv[2]; r.w = rv[3];
        *reinterpret_cast<f32x4*>(op) = r;
        wp += WSZ;
        op += NPOS;
    }
}

__global__ __launch_bounds__(256) void roi_align_v17(
    const float* __restrict__ fm,
    const float* __restrict__ boxes,
    const int*   __restrict__ box_idx,
    float*       __restrict__ out)
{
    __shared__ float B0[ITEM_CH * WSZ];   // 8 KB
    __shared__ float B1[ITEM_CH * WSZ];   // 8 KB

    int bid  = blockIdx.x;
    int xcd  = bid & 7;
    int bxl  = bid >> 3;
    int cb_x = xcd * 32;
    int m0   = 2 * bxl;
    int m1   = m0 + 1;

    int t  = threadIdx.x;
    int wv = t >> 6;
    int l  = t & 63;
    int qq = min(l, 48);

    // all global scalar data up front; keep-alives stop load sinking
    SC s0 = mk_sc(boxes, box_idx, m0);
    SC s1 = mk_sc(boxes, box_idx, m1);
    asm volatile("" :: "v"(s1.bi), "v"(s1.yLo), "v"(s1.xW),
                       "v"(s1.x1), "v"(s1.y1), "v"(s1.sx), "v"(s1.sy));

    WT W0, W1;
    mk_wt(s0, qq, W0);
    mk_wt(s1, qq, W1);

    // prologue: D0 -> B0, D1 -> B1
    stage(fm, s0, cb_x + 0 * ITEM_CH, wv, l, B0);
    stage(fm, s0, cb_x + 1 * ITEM_CH, wv, l, B1);

    // pipeline: wait D(j) -> comp(bc) -> restage item j+2 into bc.
    // Issued after D(j) at wait time: D(j+1):2 + s(j-1):2 <= 4 -> vmcnt(4)
    // guarantees D(j) done (in-order retirement; also paces at older stores'
    // L2-acceptance = write-drain rate, which is the desired throttle).
    #pragma unroll
    for (int j = 0; j < 8; ++j) {
        float* bc = (j & 1) ? B1 : B0;
        int mcur  = (j < 4) ? m0 : m1;
        int cb    = cb_x + (j & 3) * ITEM_CH;

        if (j == 0) {
            asm volatile("s_waitcnt vmcnt(2)" ::: "memory");  // only D1 newer
        } else {
            asm volatile("s_waitcnt vmcnt(4)" ::: "memory");
        }

        if (l < 49) {
            if (j < 4) comp(bc, W0, out, mcur, cb, wv, l);
            else       comp(bc, W1, out, mcur, cb, wv, l);
        }

        if (j < 6) {
            int jn = j + 2;
            stage(fm, (jn < 4) ? s0 : s1, cb_x + (jn & 3) * ITEM_CH, wv, l, bc);
        }
    }
}

extern "C" void kernel_launch(void* const* d_in, const int* in_sizes, int n_in,
                              void* d_out, int out_size, void* d_ws, size_t ws_size,
                              hipStream_t stream) {
    const float* fm      = (const float*)d_in[0];
    const float* boxes   = (const float*)d_in[1];
    const int*   box_idx = (const int*)d_in[2];
    float* out = (float*)d_out;

    dim3 block(256);
    dim3 grid(2048);
    hipLaunchKernelGGL(roi_align_v17, grid, block, 0, stream,
                       fm, boxes, box_idx, out);
}